// Round 2
// baseline (2830.835 us; speedup 1.0000x reference)
//
#include <hip/hip_runtime.h>
#include <math.h>

namespace {
constexpr int kN = 100000;   // nodes
constexpr int kE = 1600000;  // edges
constexpr int kF = 128;      // input features
constexpr int kH = 16;       // hidden
constexpr int kC = 40;       // classes

// p1 = x @ W_l1, r1 = x @ W_r1   (weights staged in LDS, broadcast reads)
__global__ __launch_bounds__(256) void proj1_kernel(
    const float* __restrict__ x,
    const float* __restrict__ Wl,
    const float* __restrict__ Wr,
    float* __restrict__ p1,
    float* __restrict__ r1)
{
    __shared__ float sWl[kF * kH];
    __shared__ float sWr[kF * kH];
    for (int i = threadIdx.x; i < kF * kH; i += 256) {
        sWl[i] = Wl[i];
        sWr[i] = Wr[i];
    }
    __syncthreads();
    int node = blockIdx.x * 256 + threadIdx.x;
    if (node >= kN) return;
    const float4* xr = reinterpret_cast<const float4*>(x + (size_t)node * kF);
    float accL[kH];
    float accR[kH];
#pragma unroll
    for (int j = 0; j < kH; ++j) { accL[j] = 0.f; accR[j] = 0.f; }
    for (int k4 = 0; k4 < kF / 4; ++k4) {
        float4 v = xr[k4];
        float vv[4] = {v.x, v.y, v.z, v.w};
#pragma unroll
        for (int u = 0; u < 4; ++u) {
            const float* wl = &sWl[(k4 * 4 + u) * kH];
            const float* wr = &sWr[(k4 * 4 + u) * kH];
            float s = vv[u];
#pragma unroll
            for (int j = 0; j < kH; ++j) {
                accL[j] = fmaf(s, wl[j], accL[j]);
                accR[j] = fmaf(s, wr[j], accR[j]);
            }
        }
    }
    float4* p1r = reinterpret_cast<float4*>(p1 + (size_t)node * kH);
    float4* r1r = reinterpret_cast<float4*>(r1 + (size_t)node * kH);
#pragma unroll
    for (int q = 0; q < 4; ++q) {
        p1r[q] = make_float4(accL[4*q], accL[4*q+1], accL[4*q+2], accL[4*q+3]);
        r1r[q] = make_float4(accR[4*q], accR[4*q+1], accR[4*q+2], accR[4*q+3]);
    }
}

// One thread per edge: osum[dst] += feat[src] (16 fp32 atomics), optional degree count.
__global__ __launch_bounds__(256) void agg_kernel(
    const int* __restrict__ src,
    const int* __restrict__ dst,
    const float* __restrict__ feat,
    float* __restrict__ osum,
    float* __restrict__ cnt)   // may be null
{
    int e = blockIdx.x * 256 + threadIdx.x;
    if (e >= kE) return;
    int s = src[e];
    int d = dst[e];
    const float4* fp = reinterpret_cast<const float4*>(feat + (size_t)s * kH);
    float4 f0 = fp[0], f1 = fp[1], f2 = fp[2], f3 = fp[3];
    float* o = osum + (size_t)d * kH;
    atomicAdd(o + 0,  f0.x); atomicAdd(o + 1,  f0.y);
    atomicAdd(o + 2,  f0.z); atomicAdd(o + 3,  f0.w);
    atomicAdd(o + 4,  f1.x); atomicAdd(o + 5,  f1.y);
    atomicAdd(o + 6,  f1.z); atomicAdd(o + 7,  f1.w);
    atomicAdd(o + 8,  f2.x); atomicAdd(o + 9,  f2.y);
    atomicAdd(o + 10, f2.z); atomicAdd(o + 11, f2.w);
    atomicAdd(o + 12, f3.x); atomicAdd(o + 13, f3.y);
    atomicAdd(o + 14, f3.z); atomicAdd(o + 15, f3.w);
    if (cnt != nullptr) atomicAdd(cnt + d, 1.0f);
}

// h = relu(s1 / max(cnt,1) + b1 + r1), float4-granular
__global__ __launch_bounds__(256) void mk_h_kernel(
    const float* __restrict__ s1,
    const float* __restrict__ r1,
    const float* __restrict__ cnt,
    const float* __restrict__ b1,
    float* __restrict__ h)
{
    int i = blockIdx.x * 256 + threadIdx.x;          // float4 index
    constexpr int total = kN * kH / 4;
    if (i >= total) return;
    int node = i >> 2;
    int quad = i & 3;
    float inv = 1.0f / fmaxf(cnt[node], 1.0f);
    float4 sv = reinterpret_cast<const float4*>(s1)[i];
    float4 rv = reinterpret_cast<const float4*>(r1)[i];
    float4 bv = reinterpret_cast<const float4*>(b1)[quad];
    float4 hv;
    hv.x = fmaxf(fmaf(sv.x, inv, bv.x + rv.x), 0.f);
    hv.y = fmaxf(fmaf(sv.y, inv, bv.y + rv.y), 0.f);
    hv.z = fmaxf(fmaf(sv.z, inv, bv.z + rv.z), 0.f);
    hv.w = fmaxf(fmaf(sv.w, inv, bv.w + rv.w), 0.f);
    reinterpret_cast<float4*>(h)[i] = hv;
}

// out = log_softmax((s2/cnt) @ W_l2 + b2 + h @ W_r2)
__global__ __launch_bounds__(256) void out_kernel(
    const float* __restrict__ s2,
    const float* __restrict__ h,
    const float* __restrict__ cnt,
    const float* __restrict__ Wl,
    const float* __restrict__ b2,
    const float* __restrict__ Wr,
    float* __restrict__ out)
{
    __shared__ float sWl[kH * kC];
    __shared__ float sWr[kH * kC];
    __shared__ float sb[kC];
    for (int i = threadIdx.x; i < kH * kC; i += 256) {
        sWl[i] = Wl[i];
        sWr[i] = Wr[i];
    }
    if (threadIdx.x < kC) sb[threadIdx.x] = b2[threadIdx.x];
    __syncthreads();
    int node = blockIdx.x * 256 + threadIdx.x;
    if (node >= kN) return;
    float inv = 1.0f / fmaxf(cnt[node], 1.0f);
    float a[kH], hh[kH];
    const float4* s2r = reinterpret_cast<const float4*>(s2 + (size_t)node * kH);
    const float4* hr  = reinterpret_cast<const float4*>(h  + (size_t)node * kH);
#pragma unroll
    for (int q = 0; q < 4; ++q) {
        float4 sv = s2r[q];
        a[4*q+0] = sv.x * inv; a[4*q+1] = sv.y * inv;
        a[4*q+2] = sv.z * inv; a[4*q+3] = sv.w * inv;
        float4 hv = hr[q];
        hh[4*q+0] = hv.x; hh[4*q+1] = hv.y;
        hh[4*q+2] = hv.z; hh[4*q+3] = hv.w;
    }
    float o[kC];
#pragma unroll
    for (int j = 0; j < kC; ++j) o[j] = sb[j];
    for (int k = 0; k < kH; ++k) {
        float av = a[k], hv = hh[k];
        const float* wl = &sWl[k * kC];
        const float* wr = &sWr[k * kC];
#pragma unroll
        for (int j = 0; j < kC; ++j) {
            o[j] = fmaf(av, wl[j], o[j]);
            o[j] = fmaf(hv, wr[j], o[j]);
        }
    }
    float m = o[0];
#pragma unroll
    for (int j = 1; j < kC; ++j) m = fmaxf(m, o[j]);
    float ssum = 0.f;
#pragma unroll
    for (int j = 0; j < kC; ++j) ssum += expf(o[j] - m);
    float ls = logf(ssum);
    float4* outr = reinterpret_cast<float4*>(out + (size_t)node * kC);
#pragma unroll
    for (int q = 0; q < kC / 4; ++q) {
        float4 v;
        v.x = o[4*q+0] - m - ls;
        v.y = o[4*q+1] - m - ls;
        v.z = o[4*q+2] - m - ls;
        v.w = o[4*q+3] - m - ls;
        outr[q] = v;
    }
}

} // namespace

extern "C" void kernel_launch(void* const* d_in, const int* in_sizes, int n_in,
                              void* d_out, int out_size, void* d_ws, size_t ws_size,
                              hipStream_t stream)
{
    const float* x   = (const float*)d_in[0];
    const int*   ei  = (const int*)d_in[1];   // int inputs staged as int32
    // d_in[2] = edge_weight (unused by SAGEConv)
    const float* Wl1 = (const float*)d_in[3];
    const float* b1  = (const float*)d_in[4];
    const float* Wr1 = (const float*)d_in[5];
    const float* Wl2 = (const float*)d_in[6];
    const float* b2  = (const float*)d_in[7];
    const float* Wr2 = (const float*)d_in[8];
    float* out = (float*)d_out;

    char* ws = (char*)d_ws;
    size_t off = 0;
    auto alloc = [&](size_t bytes) -> float* {
        char* p = ws + off;
        off += (bytes + 255) & ~(size_t)255;
        return (float*)p;
    };
    const size_t nh_bytes = (size_t)kN * kH * sizeof(float);
    float* cnt  = alloc((size_t)kN * sizeof(float));
    float* p1   = alloc(nh_bytes);
    float* r1   = alloc(nh_bytes);
    float* s1   = alloc(nh_bytes);
    float* hbuf = alloc(nh_bytes);
    float* s2   = alloc(nh_bytes);

    hipMemsetAsync(cnt, 0, (size_t)kN * sizeof(float), stream);
    hipMemsetAsync(s1,  0, nh_bytes, stream);
    hipMemsetAsync(s2,  0, nh_bytes, stream);

    const int* srcp = ei;        // edge_index[0]
    const int* dstp = ei + kE;   // edge_index[1]

    proj1_kernel<<<(kN + 255) / 256, 256, 0, stream>>>(x, Wl1, Wr1, p1, r1);
    agg_kernel<<<(kE + 255) / 256, 256, 0, stream>>>(srcp, dstp, p1, s1, cnt);
    mk_h_kernel<<<(kN * kH / 4 + 255) / 256, 256, 0, stream>>>(s1, r1, cnt, b1, hbuf);
    agg_kernel<<<(kE + 255) / 256, 256, 0, stream>>>(srcp, dstp, hbuf, s2, nullptr);
    out_kernel<<<(kN + 255) / 256, 256, 0, stream>>>(s2, hbuf, cnt, Wl2, b2, Wr2, out);
}

// Round 3
// 359.446 us; speedup vs baseline: 7.8755x; 7.8755x over previous
//
#include <hip/hip_runtime.h>
#include <math.h>

namespace {
constexpr int kN = 100000;   // nodes
constexpr int kE = 1600000;  // edges
constexpr int kF = 128;      // input features
constexpr int kH = 16;       // hidden
constexpr int kC = 40;       // classes
constexpr int kScanB = 256;
constexpr int kNB = (kN + kScanB - 1) / kScanB;   // 391 scan blocks

// p1 = x @ W_l1, r1 = x @ W_r1   (weights staged in LDS, broadcast reads)
__global__ __launch_bounds__(256) void proj1_kernel(
    const float* __restrict__ x,
    const float* __restrict__ Wl,
    const float* __restrict__ Wr,
    float* __restrict__ p1,
    float* __restrict__ r1)
{
    __shared__ float sWl[kF * kH];
    __shared__ float sWr[kF * kH];
    for (int i = threadIdx.x; i < kF * kH; i += 256) {
        sWl[i] = Wl[i];
        sWr[i] = Wr[i];
    }
    __syncthreads();
    int node = blockIdx.x * 256 + threadIdx.x;
    if (node >= kN) return;
    const float4* xr = reinterpret_cast<const float4*>(x + (size_t)node * kF);
    float accL[kH];
    float accR[kH];
#pragma unroll
    for (int j = 0; j < kH; ++j) { accL[j] = 0.f; accR[j] = 0.f; }
    for (int k4 = 0; k4 < kF / 4; ++k4) {
        float4 v = xr[k4];
        float vv[4] = {v.x, v.y, v.z, v.w};
#pragma unroll
        for (int u = 0; u < 4; ++u) {
            const float* wl = &sWl[(k4 * 4 + u) * kH];
            const float* wr = &sWr[(k4 * 4 + u) * kH];
            float s = vv[u];
#pragma unroll
            for (int j = 0; j < kH; ++j) {
                accL[j] = fmaf(s, wl[j], accL[j]);
                accR[j] = fmaf(s, wr[j], accR[j]);
            }
        }
    }
    float4* p1r = reinterpret_cast<float4*>(p1 + (size_t)node * kH);
    float4* r1r = reinterpret_cast<float4*>(r1 + (size_t)node * kH);
#pragma unroll
    for (int q = 0; q < 4; ++q) {
        p1r[q] = make_float4(accL[4*q], accL[4*q+1], accL[4*q+2], accL[4*q+3]);
        r1r[q] = make_float4(accR[4*q], accR[4*q+1], accR[4*q+2], accR[4*q+3]);
    }
}

// rank[e] = position of edge e within its dst bucket; deg[] becomes the histogram.
__global__ __launch_bounds__(256) void rank_kernel(
    const int* __restrict__ dst,
    int* __restrict__ deg,
    int* __restrict__ rank)
{
    int e = blockIdx.x * 256 + threadIdx.x;
    if (e >= kE) return;
    rank[e] = atomicAdd(&deg[dst[e]], 1);
}

// Exclusive scan of deg -> row_start (per-block), block totals -> bsum.
__global__ __launch_bounds__(kScanB) void scan1_kernel(
    const int* __restrict__ deg,
    int* __restrict__ row_start,
    int* __restrict__ bsum)
{
    __shared__ int sh[kScanB];
    int tid = threadIdx.x;
    int i = blockIdx.x * kScanB + tid;
    int v = (i < kN) ? deg[i] : 0;
    int x = v;
    sh[tid] = x;
    __syncthreads();
    for (int off = 1; off < kScanB; off <<= 1) {
        int t = (tid >= off) ? sh[tid - off] : 0;
        __syncthreads();
        x += t;
        sh[tid] = x;
        __syncthreads();
    }
    if (i < kN) row_start[i] = x - v;          // local exclusive
    if (tid == kScanB - 1) bsum[blockIdx.x] = x;  // block total
}

// Exclusive scan of the 391 block sums (single block of 512).
__global__ __launch_bounds__(512) void scan2_kernel(int* __restrict__ bsum)
{
    __shared__ int sh[512];
    int tid = threadIdx.x;
    int v = (tid < kNB) ? bsum[tid] : 0;
    int x = v;
    sh[tid] = x;
    __syncthreads();
    for (int off = 1; off < 512; off <<= 1) {
        int t = (tid >= off) ? sh[tid - off] : 0;
        __syncthreads();
        x += t;
        sh[tid] = x;
        __syncthreads();
    }
    if (tid < kNB) bsum[tid] = x - v;          // exclusive block offsets
}

// row_start[i] += block offset  -> global exclusive scan
__global__ __launch_bounds__(kScanB) void scan3_kernel(
    int* __restrict__ row_start,
    const int* __restrict__ bsum)
{
    int i = blockIdx.x * kScanB + threadIdx.x;
    if (i < kN) row_start[i] += bsum[blockIdx.x];
}

// eidx[row_start[dst] + rank] = src   (no atomics)
__global__ __launch_bounds__(256) void scatter_kernel(
    const int* __restrict__ src,
    const int* __restrict__ dst,
    const int* __restrict__ rank,
    const int* __restrict__ row_start,
    int* __restrict__ eidx)
{
    int e = blockIdx.x * 256 + threadIdx.x;
    if (e >= kE) return;
    eidx[row_start[dst[e]] + rank[e]] = src[e];
}

// Per (node, f): mean over neighbors of p1, then h = relu(mean + b1 + r1)
__global__ __launch_bounds__(256) void gather1_kernel(
    const int* __restrict__ row_start,
    const int* __restrict__ deg,
    const int* __restrict__ eidx,
    const float* __restrict__ p1,
    const float* __restrict__ r1,
    const float* __restrict__ b1,
    float* __restrict__ h)
{
    int t = blockIdx.x * 256 + threadIdx.x;
    if (t >= kN * kH) return;
    int node = t >> 4;
    int f = t & 15;
    int start = row_start[node];
    int dgr = deg[node];
    float sum = 0.f;
    for (int i = 0; i < dgr; ++i) {
        int s = eidx[start + i];
        sum += p1[(size_t)s * kH + f];
    }
    float inv = 1.0f / fmaxf((float)dgr, 1.0f);
    h[t] = fmaxf(fmaf(sum, inv, b1[f] + r1[t]), 0.f);
}

// Per (node, f): s2 = mean over neighbors of h (pre-normalized)
__global__ __launch_bounds__(256) void gather2_kernel(
    const int* __restrict__ row_start,
    const int* __restrict__ deg,
    const int* __restrict__ eidx,
    const float* __restrict__ h,
    float* __restrict__ s2)
{
    int t = blockIdx.x * 256 + threadIdx.x;
    if (t >= kN * kH) return;
    int node = t >> 4;
    int f = t & 15;
    int start = row_start[node];
    int dgr = deg[node];
    float sum = 0.f;
    for (int i = 0; i < dgr; ++i) {
        int s = eidx[start + i];
        sum += h[(size_t)s * kH + f];
    }
    s2[t] = sum / fmaxf((float)dgr, 1.0f);
}

// out = log_softmax(s2 @ W_l2 + b2 + h @ W_r2)
__global__ __launch_bounds__(256) void out_kernel(
    const float* __restrict__ s2,
    const float* __restrict__ h,
    const float* __restrict__ Wl,
    const float* __restrict__ b2,
    const float* __restrict__ Wr,
    float* __restrict__ out)
{
    __shared__ float sWl[kH * kC];
    __shared__ float sWr[kH * kC];
    __shared__ float sb[kC];
    for (int i = threadIdx.x; i < kH * kC; i += 256) {
        sWl[i] = Wl[i];
        sWr[i] = Wr[i];
    }
    if (threadIdx.x < kC) sb[threadIdx.x] = b2[threadIdx.x];
    __syncthreads();
    int node = blockIdx.x * 256 + threadIdx.x;
    if (node >= kN) return;
    float a[kH], hh[kH];
    const float4* s2r = reinterpret_cast<const float4*>(s2 + (size_t)node * kH);
    const float4* hr  = reinterpret_cast<const float4*>(h  + (size_t)node * kH);
#pragma unroll
    for (int q = 0; q < 4; ++q) {
        float4 sv = s2r[q];
        a[4*q+0] = sv.x; a[4*q+1] = sv.y; a[4*q+2] = sv.z; a[4*q+3] = sv.w;
        float4 hv = hr[q];
        hh[4*q+0] = hv.x; hh[4*q+1] = hv.y; hh[4*q+2] = hv.z; hh[4*q+3] = hv.w;
    }
    float o[kC];
#pragma unroll
    for (int j = 0; j < kC; ++j) o[j] = sb[j];
    for (int k = 0; k < kH; ++k) {
        float av = a[k], hv = hh[k];
        const float* wl = &sWl[k * kC];
        const float* wr = &sWr[k * kC];
#pragma unroll
        for (int j = 0; j < kC; ++j) {
            o[j] = fmaf(av, wl[j], o[j]);
            o[j] = fmaf(hv, wr[j], o[j]);
        }
    }
    float m = o[0];
#pragma unroll
    for (int j = 1; j < kC; ++j) m = fmaxf(m, o[j]);
    float ssum = 0.f;
#pragma unroll
    for (int j = 0; j < kC; ++j) ssum += expf(o[j] - m);
    float ls = logf(ssum);
    float4* outr = reinterpret_cast<float4*>(out + (size_t)node * kC);
#pragma unroll
    for (int q = 0; q < kC / 4; ++q) {
        float4 v;
        v.x = o[4*q+0] - m - ls;
        v.y = o[4*q+1] - m - ls;
        v.z = o[4*q+2] - m - ls;
        v.w = o[4*q+3] - m - ls;
        outr[q] = v;
    }
}

} // namespace

extern "C" void kernel_launch(void* const* d_in, const int* in_sizes, int n_in,
                              void* d_out, int out_size, void* d_ws, size_t ws_size,
                              hipStream_t stream)
{
    const float* x   = (const float*)d_in[0];
    const int*   ei  = (const int*)d_in[1];   // int inputs staged as int32
    // d_in[2] = edge_weight (unused by SAGEConv)
    const float* Wl1 = (const float*)d_in[3];
    const float* b1  = (const float*)d_in[4];
    const float* Wr1 = (const float*)d_in[5];
    const float* Wl2 = (const float*)d_in[6];
    const float* b2  = (const float*)d_in[7];
    const float* Wr2 = (const float*)d_in[8];
    float* out = (float*)d_out;

    char* ws = (char*)d_ws;
    size_t off = 0;
    auto alloc = [&](size_t bytes) -> void* {
        char* p = ws + off;
        off += (bytes + 255) & ~(size_t)255;
        return (void*)p;
    };
    const size_t nh_bytes = (size_t)kN * kH * sizeof(float);
    int*   deg       = (int*)alloc((size_t)kN * sizeof(int));
    int*   row_start = (int*)alloc((size_t)kN * sizeof(int));
    int*   bsum      = (int*)alloc(512 * sizeof(int));
    int*   eidx      = (int*)alloc((size_t)kE * sizeof(int));
    float* p1        = (float*)alloc(nh_bytes);
    float* r1        = (float*)alloc(nh_bytes);
    float* hbuf      = (float*)alloc(nh_bytes);   // aliases rank (int) before gather1
    float* s2        = p1;                        // p1 dead after gather1

    int* rank = (int*)hbuf;   // rank[e] lives where h will live; h written after rank consumed

    const int* srcp = ei;        // edge_index[0]
    const int* dstp = ei + kE;   // edge_index[1]

    hipMemsetAsync(deg, 0, (size_t)kN * sizeof(int), stream);

    proj1_kernel<<<(kN + 255) / 256, 256, 0, stream>>>(x, Wl1, Wr1, p1, r1);

    // hbuf only holds rank for kE ints = 6.4MB but nh_bytes = 6.4MB too: exact fit
    rank_kernel<<<(kE + 255) / 256, 256, 0, stream>>>(dstp, deg, rank);
    scan1_kernel<<<kNB, kScanB, 0, stream>>>(deg, row_start, bsum);
    scan2_kernel<<<1, 512, 0, stream>>>(bsum);
    scan3_kernel<<<kNB, kScanB, 0, stream>>>(row_start, bsum);
    scatter_kernel<<<(kE + 255) / 256, 256, 0, stream>>>(srcp, dstp, rank, row_start, eidx);

    gather1_kernel<<<(kN * kH) / 256, 256, 0, stream>>>(row_start, deg, eidx, p1, r1, b1, hbuf);
    gather2_kernel<<<(kN * kH) / 256, 256, 0, stream>>>(row_start, deg, eidx, hbuf, s2);
    out_kernel<<<(kN + 255) / 256, 256, 0, stream>>>(s2, hbuf, Wl2, b2, Wr2, out);
}